// Round 18
// baseline (511.200 us; speedup 1.0000x reference)
//
#include <hip/hip_runtime.h>

typedef short v8s __attribute__((ext_vector_type(8)));
typedef float v4f __attribute__((ext_vector_type(4)));
typedef float v16f __attribute__((ext_vector_type(16)));

#define T_TOK 2048
#define DD 2048
#define FF 4096
#define EE 8
#define BM 128
#define BN 128
#define BK 64
#define MT_MAX 40
#define MAXROWS 5120

// workspace layout (bytes)
#define WS_COUNTS 0
#define WS_FILL   32
#define WS_ROWOFF 64
#define WS_TOPE   128
#define WS_TOPW   (WS_TOPE + T_TOK * 2 * 4)   // 16512
#define WS_IDS    (WS_TOPW + T_TOK * 2 * 4)   // 32896
#define WS_WTS    (WS_IDS + MAXROWS * 4)      // 53376
#define WS_ZERO   (WS_WTS + MAXROWS * 4)      // 73856 zeroed each launch
#define WS_SLOT   73856ul                     // int slot[T_TOK*2] (fully written)
#define WS_XB     90368ul                     // bf16 X [2048][2048] = 8 MB
#define WS_H      (WS_XB + 8388608ul)         // bf16 H [5120][4096] = 41.9 MB
#define WS_O      (WS_H + 41943040ul)         // bf16 O [5120][2048] = 21 MB

// chunk swizzle within a [row][64 bf16] LDS tile (128B rows, 8x16B chunks)
#define SW(r)      ((((r) ^ ((r) >> 3)) & 7))
#define SWZ(r, kb) ((r) * 128 + ((kb) ^ (SW(r) << 4)))

#define VMCNT16() asm volatile("s_waitcnt vmcnt(16)" ::: "memory")
#define VMCNT8()  asm volatile("s_waitcnt vmcnt(8)" ::: "memory")
#define VMCNT0()  asm volatile("s_waitcnt vmcnt(0)" ::: "memory")
#define LGKM0()   asm volatile("s_waitcnt lgkmcnt(0)" ::: "memory")
#define BARR()    __builtin_amdgcn_s_barrier()
#define SCHEDB()  __builtin_amdgcn_sched_barrier(0)

static __device__ __forceinline__ short f2bf(float f) {
  return __builtin_bit_cast(short, static_cast<__bf16>(f));
}
static __device__ __forceinline__ float bf2f(unsigned short u) {
  return __builtin_bit_cast(float, ((unsigned)u) << 16);
}

// async global->LDS 16B/lane; LDS dest = wave-uniform base + lane*16 (HW).
static __device__ __forceinline__ void gload_lds16(const void* g, void* l) {
  __builtin_amdgcn_global_load_lds(
      (const __attribute__((address_space(1))) unsigned int*)g,
      (__attribute__((address_space(3))) unsigned int*)l, 16, 0, 0);
}

// ---------------- router: fp32 logits, softmax, top-2; also emits X->bf16 ----
__global__ __launch_bounds__(256) void router_k(
    const float* __restrict__ x, const float* __restrict__ gw,
    int* __restrict__ counts, int* __restrict__ tope, float* __restrict__ topw,
    unsigned short* __restrict__ xb) {
  const int lane = threadIdx.x & 63;
  const int t = blockIdx.x * 4 + (threadIdx.x >> 6);
  if (t >= T_TOK) return;
  float acc[EE] = {0.f, 0.f, 0.f, 0.f, 0.f, 0.f, 0.f, 0.f};
  const float* xr = x + (size_t)t * DD;
  unsigned short* xo = xb + (size_t)t * DD;
  for (int i = 0; i < DD / 64; ++i) {
    int k = i * 64 + lane;
    float xv = xr[k];
    xo[k] = (unsigned short)f2bf(xv);           // fused bf16 copy
    const v4f* g = (const v4f*)(gw + (size_t)k * EE);
    v4f g0 = g[0], g1 = g[1];
    acc[0] += xv * g0[0]; acc[1] += xv * g0[1]; acc[2] += xv * g0[2]; acc[3] += xv * g0[3];
    acc[4] += xv * g1[0]; acc[5] += xv * g1[1]; acc[6] += xv * g1[2]; acc[7] += xv * g1[3];
  }
  #pragma unroll
  for (int e = 0; e < EE; ++e) {
    #pragma unroll
    for (int off = 32; off > 0; off >>= 1) acc[e] += __shfl_xor(acc[e], off);
  }
  if (lane == 0) {
    float m = acc[0];
    #pragma unroll
    for (int e = 1; e < EE; ++e) m = fmaxf(m, acc[e]);
    float p[EE], s = 0.f;
    #pragma unroll
    for (int e = 0; e < EE; ++e) { p[e] = expf(acc[e] - m); s += p[e]; }
    float inv = 1.f / s;
    #pragma unroll
    for (int e = 0; e < EE; ++e) p[e] *= inv;
    int e1 = 0;
    #pragma unroll
    for (int e = 1; e < EE; ++e) if (p[e] > p[e1]) e1 = e;
    int e2 = (e1 == 0) ? 1 : 0;
    #pragma unroll
    for (int e = 0; e < EE; ++e) if (e != e1 && p[e] > p[e2]) e2 = e;
    tope[2 * t] = e1;  tope[2 * t + 1] = e2;
    topw[2 * t] = p[e1]; topw[2 * t + 1] = p[e2];
    atomicAdd(&counts[e1], 1);
    atomicAdd(&counts[e2], 1);
  }
}

// ------- scatter (single block; fuses offsets_k): rowoff then slot fill -------
__global__ __launch_bounds__(256) void scatter_k(
    const int* __restrict__ tope, const float* __restrict__ topw,
    const int* __restrict__ counts, int* __restrict__ rowoff,
    int* __restrict__ fill, int* __restrict__ ids, float* __restrict__ wts,
    int* __restrict__ slot) {
  if (threadIdx.x == 0) {
    int off = 0;
    #pragma unroll
    for (int e = 0; e < EE; ++e) {
      rowoff[e] = off;
      off += ((counts[e] + BM - 1) / BM) * BM;
    }
  }
  __syncthreads();
  for (int t = threadIdx.x; t < T_TOK; t += 256) {
    #pragma unroll
    for (int j = 0; j < 2; ++j) {
      int e = tope[2 * t + j];
      int pos = rowoff[e] + atomicAdd(&fill[e], 1);
      ids[pos] = t;
      wts[pos] = topw[2 * t + j];
      slot[2 * t + j] = pos;
    }
  }
}

static __device__ __forceinline__ int find_expert(
    const int* counts, const int* rowoff, int mt) {
  int expert = -1;
  #pragma unroll
  for (int e = 0; e < EE; ++e) {
    int rs = rowoff[e];
    int tl = (counts[e] + BM - 1) / BM;
    if (mt * BM >= rs && mt * BM < rs + tl * BM) expert = e;
  }
  return expert;
}

// XCD-aware bijective swizzle, mt-fastest. nwg % 8 == 0 for both grids.
static __device__ __forceinline__ void xcd_map(int* nt, int* mt) {
  int gx = gridDim.x, gy = gridDim.y;
  int nwg = gx * gy;
  int lin = blockIdx.y * gx + blockIdx.x;
  int q = nwg >> 3;
  int s = (lin & 7) * q + (lin >> 3);
  *nt = s / gy;
  *mt = s % gy;
}

// ---------------- GEMM1: H = silu(Xb@W1) * (Xb@W3), bf16 out ----------------
// R15/R17 verbatim: single-phase ALDS drain + one-ahead B prefetch.
// Deeper counted-vmcnt pipelines raced 3/3 (R10/R11/R16) — retired.
__global__ __launch_bounds__(256, 2) void gemm1_k(
    const unsigned short* __restrict__ xb, const float* __restrict__ w1,
    const float* __restrict__ w3, const int* __restrict__ counts,
    const int* __restrict__ rowoff, const int* __restrict__ ids,
    unsigned short* __restrict__ H) {
  int nt, mt;
  xcd_map(&nt, &mt);
  const int expert = find_expert(counts, rowoff, mt);
  if (expert < 0) return;
  const int m0 = mt * BM, n0 = nt * BN;

  __shared__ unsigned short sA[BM * BK];
  __shared__ unsigned short sB0[BN * BK];
  __shared__ unsigned short sB1[BN * BK];

  const int tid = threadIdx.x;
  const int lane = tid & 63;
  const int wid = tid >> 6;
  const int wm = (wid >> 1) * 64, wn = (wid & 1) * 64;
  const int l32 = lane & 31;
  const int khi = lane >> 5;

  const unsigned short* ga[4];
  #pragma unroll
  for (int i = 0; i < 4; ++i) {
    int r = wid * 32 + i * 8 + (lane >> 3);
    ga[i] = xb + (size_t)ids[m0 + r] * DD + (((lane & 7) ^ SW(r)) << 3);
  }

  const int b_f4 = (tid & 31) * 4;
  const int b_k8 = (tid >> 5) * 8;
  const float* wb1 = w1 + (size_t)expert * DD * FF + n0 + b_f4 + (size_t)b_k8 * FF;
  const float* wb3 = w3 + (size_t)expert * DD * FF + n0 + b_f4 + (size_t)b_k8 * FF;

  v4f r1[8], r3[8];
  #define G1_ALDS(KT) { _Pragma("unroll") for (int i_ = 0; i_ < 4; ++i_)        \
      gload_lds16(ga[i_] + (size_t)(KT) * BK,                                   \
                  (char*)sA + (wid * 32 + i_ * 8) * 128); }
  #define G1_BL(KT) {                                                           \
      const float* p_ = wb1 + (size_t)(KT) * BK * FF;                           \
      _Pragma("unroll") for (int j_ = 0; j_ < 8; ++j_)                          \
        r1[j_] = *(const v4f*)(p_ + (size_t)j_ * FF);                           \
      p_ = wb3 + (size_t)(KT) * BK * FF;                                        \
      _Pragma("unroll") for (int j_ = 0; j_ < 8; ++j_)                          \
        r3[j_] = *(const v4f*)(p_ + (size_t)j_ * FF); }
  #define G1_BW() { _Pragma("unroll") for (int c_ = 0; c_ < 4; ++c_) {          \
      v8s h1_, h3_;                                                             \
      _Pragma("unroll") for (int j_ = 0; j_ < 8; ++j_) {                        \
        h1_[j_] = f2bf(r1[j_][c_]); h3_[j_] = f2bf(r3[j_][c_]); }               \
      *(v8s*)((char*)sB0 + SWZ(b_f4 + c_, b_k8 * 2)) = h1_;                     \
      *(v8s*)((char*)sB1 + SWZ(b_f4 + c_, b_k8 * 2)) = h3_; } }

  v16f acc1[2][2], acc3[2][2];
  #pragma unroll
  for (int i = 0; i < 2; ++i)
    #pragma unroll
    for (int j = 0; j < 2; ++j) {
      acc1[i][j] = (v16f)(0.f);
      acc3[i][j] = (v16f)(0.f);
    }

  G1_BL(0);                        // B(0) prefetch

  for (int kt = 0; kt < DD / BK; ++kt) {
    G1_ALDS(kt);                   // A(kt) -> sA async, zero VGPR
    SCHEDB();
    G1_BW();                       // consume B(kt) regs (cvt+write)
    if (kt + 1 < DD / BK) {
      G1_BL(kt + 1);               // issue B(kt+1); flies across compute
      SCHEDB();
      VMCNT16();                   // wait the 4 A-gloads only
    } else {
      VMCNT0();
    }
    LGKM0(); BARR();
    SCHEDB();
    #pragma unroll
    for (int ks = 0; ks < 4; ++ks) {
      const int kb = (ks * 2 + khi) * 16;
      v8s a[2], b1[2], b3[2];
      #pragma unroll
      for (int m = 0; m < 2; ++m)
        a[m] = *(const v8s*)((const char*)sA + SWZ(wm + m * 32 + l32, kb));
      #pragma unroll
      for (int n = 0; n < 2; ++n) {
        b1[n] = *(const v8s*)((const char*)sB0 + SWZ(wn + n * 32 + l32, kb));
        b3[n] = *(const v8s*)((const char*)sB1 + SWZ(wn + n * 32 + l32, kb));
      }
      #pragma unroll
      for (int m = 0; m < 2; ++m)
        #pragma unroll
        for (int n = 0; n < 2; ++n) {
          acc1[m][n] = __builtin_amdgcn_mfma_f32_32x32x16_bf16(a[m], b1[n], acc1[m][n], 0, 0, 0);
          acc3[m][n] = __builtin_amdgcn_mfma_f32_32x32x16_bf16(a[m], b3[n], acc3[m][n], 0, 0, 0);
        }
    }
    BARR();                        // all waves done reading sA/sB
  }
  // C/D layout (32x32): col = lane&31, row = (r&3) + 8*(r>>2) + 4*(lane>>5)
  #pragma unroll
  for (int m = 0; m < 2; ++m)
    #pragma unroll
    for (int n = 0; n < 2; ++n)
      #pragma unroll
      for (int r = 0; r < 16; ++r) {
        int row = wm + m * 32 + (r & 3) + 8 * (r >> 2) + 4 * khi;
        int col = wn + n * 32 + l32;
        float g = acc1[m][n][r];
        float u = acc3[m][n][r];
        float hv = (g / (1.f + expf(-g))) * u;
        H[(size_t)(m0 + row) * FF + (n0 + col)] = (unsigned short)f2bf(hv);
      }
}

// ---------------- GEMM2: O[row] = H[row] @ W2 (raw, unweighted) ----------------
// R15/R17 verbatim: single B panel, plain bf16 stores to O (atomic-free).
__global__ __launch_bounds__(256, 2) void gemm2_k(
    const unsigned short* __restrict__ H, const float* __restrict__ w2,
    const int* __restrict__ counts, const int* __restrict__ rowoff,
    unsigned short* __restrict__ O) {
  int nt, mt;
  xcd_map(&nt, &mt);
  const int expert = find_expert(counts, rowoff, mt);
  if (expert < 0) return;
  const int m0 = mt * BM, n0 = nt * BN;

  __shared__ unsigned short sA[BM * BK];
  __shared__ unsigned short sB[BN * BK];

  const int tid = threadIdx.x;
  const int lane = tid & 63;
  const int wid = tid >> 6;
  const int wm = (wid >> 1) * 64, wn = (wid & 1) * 64;
  const int l32 = lane & 31;
  const int khi = lane >> 5;

  const unsigned short* ga[4];
  #pragma unroll
  for (int i = 0; i < 4; ++i) {
    int r = wid * 32 + i * 8 + (lane >> 3);
    ga[i] = H + (size_t)(m0 + r) * FF + (((lane & 7) ^ SW(r)) << 3);
  }

  const int b_f4 = (tid & 31) * 4;   // output cols (d)
  const int b_k8 = (tid >> 5) * 8;   // k rows (f)
  const float* wb = w2 + (size_t)expert * FF * DD + n0 + b_f4 + (size_t)b_k8 * DD;

  v4f rb[8];
  #define G2_ALDS(KT) { _Pragma("unroll") for (int i_ = 0; i_ < 4; ++i_)        \
      gload_lds16(ga[i_] + (size_t)(KT) * BK,                                   \
                  (char*)sA + (wid * 32 + i_ * 8) * 128); }
  #define G2_BL(KT) { const float* p_ = wb + (size_t)(KT) * BK * DD;            \
      _Pragma("unroll") for (int j_ = 0; j_ < 8; ++j_)                          \
        rb[j_] = *(const v4f*)(p_ + (size_t)j_ * DD); }
  #define G2_BW() { _Pragma("unroll") for (int c_ = 0; c_ < 4; ++c_) {          \
      v8s h_;                                                                   \
      _Pragma("unroll") for (int j_ = 0; j_ < 8; ++j_) h_[j_] = f2bf(rb[j_][c_]);\
      *(v8s*)((char*)sB + SWZ(b_f4 + c_, b_k8 * 2)) = h_; } }

  v16f acc[2][2];
  #pragma unroll
  for (int i = 0; i < 2; ++i)
    #pragma unroll
    for (int j = 0; j < 2; ++j) acc[i][j] = (v16f)(0.f);

  G2_BL(0);

  for (int kt = 0; kt < FF / BK; ++kt) {
    G2_ALDS(kt);
    SCHEDB();
    G2_BW();
    if (kt + 1 < FF / BK) {
      G2_BL(kt + 1);
      SCHEDB();
      VMCNT8();                    // wait the 4 A-gloads only
    } else {
      VMCNT0();
    }
    LGKM0(); BARR();
    SCHEDB();
    #pragma unroll
    for (int ks = 0; ks < 4; ++ks) {
      const int kb = (ks * 2 + khi) * 16;
      v8s a[2], b[2];
      #pragma unroll
      for (int m = 0; m < 2; ++m)
        a[m] = *(const v8s*)((const char*)sA + SWZ(wm + m * 32 + l32, kb));
      #pragma unroll
      for (int n = 0; n < 2; ++n)
        b[n] = *(const v8s*)((const char*)sB + SWZ(wn + n * 32 + l32, kb));
      #pragma unroll
      for (int m = 0; m < 2; ++m)
        #pragma unroll
        for (int n = 0; n < 2; ++n)
          acc[m][n] = __builtin_amdgcn_mfma_f32_32x32x16_bf16(a[m], b[n], acc[m][n], 0, 0, 0);
    }
    BARR();
  }

  // epilogue: raw bf16 stores (coalesced)
  #pragma unroll
  for (int m = 0; m < 2; ++m)
    #pragma unroll
    for (int r = 0; r < 16; ++r) {
      int row = m0 + wm + m * 32 + (r & 3) + 8 * (r >> 2) + 4 * khi;
      #pragma unroll
      for (int n = 0; n < 2; ++n)
        O[(size_t)row * DD + n0 + wn + n * 32 + l32] =
            (unsigned short)f2bf(acc[m][n][r]);
    }
}

// ---------------- combine: out[t] = w0*O[s0] + w1*O[s1] ----------------
__global__ __launch_bounds__(256) void combine_k(
    const unsigned short* __restrict__ O, const int* __restrict__ slot,
    const float* __restrict__ wts, float* __restrict__ out) {
  const int t = blockIdx.x;
  const int d = threadIdx.x * 8;
  const int s0 = slot[2 * t], s1 = slot[2 * t + 1];
  const float w0 = wts[s0], w1 = wts[s1];
  v8s a = *(const v8s*)(O + (size_t)s0 * DD + d);
  v8s b = *(const v8s*)(O + (size_t)s1 * DD + d);
  v4f o0, o1;
  #pragma unroll
  for (int j = 0; j < 4; ++j) {
    o0[j] = w0 * bf2f((unsigned short)a[j]) + w1 * bf2f((unsigned short)b[j]);
    o1[j] = w0 * bf2f((unsigned short)a[j + 4]) + w1 * bf2f((unsigned short)b[j + 4]);
  }
  float* op = out + (size_t)t * DD + d;
  *(v4f*)op = o0;
  *(v4f*)(op + 4) = o1;
}

extern "C" void kernel_launch(void* const* d_in, const int* in_sizes, int n_in,
                              void* d_out, int out_size, void* d_ws, size_t ws_size,
                              hipStream_t stream) {
  const float* x  = (const float*)d_in[0];
  const float* gw = (const float*)d_in[1];
  const float* w1 = (const float*)d_in[2];
  const float* w3 = (const float*)d_in[3];
  const float* w2 = (const float*)d_in[4];
  float* out = (float*)d_out;
  char* ws = (char*)d_ws;

  int*   counts = (int*)(ws + WS_COUNTS);
  int*   fill   = (int*)(ws + WS_FILL);
  int*   rowoff = (int*)(ws + WS_ROWOFF);
  int*   tope   = (int*)(ws + WS_TOPE);
  float* topw   = (float*)(ws + WS_TOPW);
  int*   ids    = (int*)(ws + WS_IDS);
  float* wts    = (float*)(ws + WS_WTS);
  int*   slot   = (int*)(ws + WS_SLOT);
  unsigned short* xb = (unsigned short*)(ws + WS_XB);
  unsigned short* H  = (unsigned short*)(ws + WS_H);
  unsigned short* O  = (unsigned short*)(ws + WS_O);

  hipMemsetAsync(ws, 0, WS_ZERO, stream);

  router_k<<<T_TOK / 4, 256, 0, stream>>>(x, gw, counts, tope, topw, xb);
  scatter_k<<<1, 256, 0, stream>>>(tope, topw, counts, rowoff, fill, ids, wts, slot);
  gemm1_k<<<dim3(FF / BN, MT_MAX), 256, 0, stream>>>(xb, w1, w3, counts, rowoff, ids, H);
  gemm2_k<<<dim3(DD / BN, MT_MAX), 256, 0, stream>>>(H, w2, counts, rowoff, O);
  combine_k<<<T_TOK, 256, 0, stream>>>(O, slot, wts, out);
}

// Round 19
// 490.126 us; speedup vs baseline: 1.0430x; 1.0430x over previous
//
#include <hip/hip_runtime.h>

typedef short v8s __attribute__((ext_vector_type(8)));
typedef float v4f __attribute__((ext_vector_type(4)));
typedef float v16f __attribute__((ext_vector_type(16)));

#define T_TOK 2048
#define DD 2048
#define FF 4096
#define EE 8
#define BM 128
#define BN 128
#define BK 64
#define MT_MAX 40
#define MAXROWS 5120

// workspace layout (bytes)
#define WS_COUNTS 0
#define WS_FILL   32
#define WS_ROWOFF 64
#define WS_TOPE   128
#define WS_TOPW   (WS_TOPE + T_TOK * 2 * 4)   // 16512
#define WS_IDS    (WS_TOPW + T_TOK * 2 * 4)   // 32896
#define WS_WTS    (WS_IDS + MAXROWS * 4)      // 53376
#define WS_ZERO   (WS_WTS + MAXROWS * 4)      // 73856 zeroed each launch
#define WS_SLOT   73856ul                     // int slot[T_TOK*2] (fully written)
#define WS_XB     90368ul                     // bf16 X [2048][2048] = 8 MB
#define WS_H      (WS_XB + 8388608ul)         // bf16 H [5120][4096] = 41.9 MB
#define WS_O      (WS_H + 41943040ul)         // bf16 O [5120][2048] = 21 MB

// chunk swizzle within a [row][64 bf16] LDS tile (128B rows, 8x16B chunks)
#define SW(r)      ((((r) ^ ((r) >> 3)) & 7))
#define SWZ(r, kb) ((r) * 128 + ((kb) ^ (SW(r) << 4)))

#define VMCNT16() asm volatile("s_waitcnt vmcnt(16)" ::: "memory")
#define VMCNT8()  asm volatile("s_waitcnt vmcnt(8)" ::: "memory")
#define VMCNT0()  asm volatile("s_waitcnt vmcnt(0)" ::: "memory")
#define LGKM0()   asm volatile("s_waitcnt lgkmcnt(0)" ::: "memory")
#define BARR()    __builtin_amdgcn_s_barrier()
#define SCHEDB()  __builtin_amdgcn_sched_barrier(0)

static __device__ __forceinline__ short f2bf(float f) {
  return __builtin_bit_cast(short, static_cast<__bf16>(f));
}
static __device__ __forceinline__ float bf2f(unsigned short u) {
  return __builtin_bit_cast(float, ((unsigned)u) << 16);
}

// async global->LDS 16B/lane; LDS dest = wave-uniform base + lane*16 (HW).
static __device__ __forceinline__ void gload_lds16(const void* g, void* l) {
  __builtin_amdgcn_global_load_lds(
      (const __attribute__((address_space(1))) unsigned int*)g,
      (__attribute__((address_space(3))) unsigned int*)l, 16, 0, 0);
}

// ---------------- router: fp32 logits, softmax, top-2; also emits X->bf16 ----
__global__ __launch_bounds__(256) void router_k(
    const float* __restrict__ x, const float* __restrict__ gw,
    int* __restrict__ counts, int* __restrict__ tope, float* __restrict__ topw,
    unsigned short* __restrict__ xb) {
  const int lane = threadIdx.x & 63;
  const int t = blockIdx.x * 4 + (threadIdx.x >> 6);
  if (t >= T_TOK) return;
  float acc[EE] = {0.f, 0.f, 0.f, 0.f, 0.f, 0.f, 0.f, 0.f};
  const float* xr = x + (size_t)t * DD;
  unsigned short* xo = xb + (size_t)t * DD;
  for (int i = 0; i < DD / 64; ++i) {
    int k = i * 64 + lane;
    float xv = xr[k];
    xo[k] = (unsigned short)f2bf(xv);           // fused bf16 copy
    const v4f* g = (const v4f*)(gw + (size_t)k * EE);
    v4f g0 = g[0], g1 = g[1];
    acc[0] += xv * g0[0]; acc[1] += xv * g0[1]; acc[2] += xv * g0[2]; acc[3] += xv * g0[3];
    acc[4] += xv * g1[0]; acc[5] += xv * g1[1]; acc[6] += xv * g1[2]; acc[7] += xv * g1[3];
  }
  #pragma unroll
  for (int e = 0; e < EE; ++e) {
    #pragma unroll
    for (int off = 32; off > 0; off >>= 1) acc[e] += __shfl_xor(acc[e], off);
  }
  if (lane == 0) {
    float m = acc[0];
    #pragma unroll
    for (int e = 1; e < EE; ++e) m = fmaxf(m, acc[e]);
    float p[EE], s = 0.f;
    #pragma unroll
    for (int e = 0; e < EE; ++e) { p[e] = expf(acc[e] - m); s += p[e]; }
    float inv = 1.f / s;
    #pragma unroll
    for (int e = 0; e < EE; ++e) p[e] *= inv;
    int e1 = 0;
    #pragma unroll
    for (int e = 1; e < EE; ++e) if (p[e] > p[e1]) e1 = e;
    int e2 = (e1 == 0) ? 1 : 0;
    #pragma unroll
    for (int e = 0; e < EE; ++e) if (e != e1 && p[e] > p[e2]) e2 = e;
    tope[2 * t] = e1;  tope[2 * t + 1] = e2;
    topw[2 * t] = p[e1]; topw[2 * t + 1] = p[e2];
    atomicAdd(&counts[e1], 1);
    atomicAdd(&counts[e2], 1);
  }
}

// ---------------- per-expert padded row offsets ----------------
__global__ void offsets_k(const int* __restrict__ counts, int* __restrict__ rowoff) {
  if (threadIdx.x == 0) {
    int off = 0;
    #pragma unroll
    for (int e = 0; e < EE; ++e) {
      rowoff[e] = off;
      off += ((counts[e] + BM - 1) / BM) * BM;
    }
  }
}

// ---------------- scatter (also records each token's slot indices) ----------------
__global__ __launch_bounds__(256) void scatter_k(
    const int* __restrict__ tope, const float* __restrict__ topw,
    const int* __restrict__ rowoff, int* __restrict__ fill,
    int* __restrict__ ids, float* __restrict__ wts, int* __restrict__ slot) {
  const int t = blockIdx.x * 256 + threadIdx.x;
  if (t >= T_TOK) return;
  #pragma unroll
  for (int j = 0; j < 2; ++j) {
    int e = tope[2 * t + j];
    int pos = rowoff[e] + atomicAdd(&fill[e], 1);
    ids[pos] = t;
    wts[pos] = topw[2 * t + j];
    slot[2 * t + j] = pos;
  }
}

static __device__ __forceinline__ int find_expert(
    const int* counts, const int* rowoff, int mt) {
  int expert = -1;
  #pragma unroll
  for (int e = 0; e < EE; ++e) {
    int rs = rowoff[e];
    int tl = (counts[e] + BM - 1) / BM;
    if (mt * BM >= rs && mt * BM < rs + tl * BM) expert = e;
  }
  return expert;
}

// XCD-aware bijective swizzle, mt-fastest. nwg % 8 == 0 for both grids.
static __device__ __forceinline__ void xcd_map(int* nt, int* mt) {
  int gx = gridDim.x, gy = gridDim.y;
  int nwg = gx * gy;
  int lin = blockIdx.y * gx + blockIdx.x;
  int q = nwg >> 3;
  int s = (lin & 7) * q + (lin >> 3);
  *nt = s / gy;
  *mt = s % gy;
}

// ---------------- GEMM1: H = silu(Xb@W1) * (Xb@W3), bf16 out ----------------
// R15/R17 verbatim: single-phase ALDS drain + one-ahead B prefetch.
// Deeper counted-vmcnt pipelines raced 3/3 (R10/R11/R16) — retired.
__global__ __launch_bounds__(256, 2) void gemm1_k(
    const unsigned short* __restrict__ xb, const float* __restrict__ w1,
    const float* __restrict__ w3, const int* __restrict__ counts,
    const int* __restrict__ rowoff, const int* __restrict__ ids,
    unsigned short* __restrict__ H) {
  int nt, mt;
  xcd_map(&nt, &mt);
  const int expert = find_expert(counts, rowoff, mt);
  if (expert < 0) return;
  const int m0 = mt * BM, n0 = nt * BN;

  __shared__ unsigned short sA[BM * BK];
  __shared__ unsigned short sB0[BN * BK];
  __shared__ unsigned short sB1[BN * BK];

  const int tid = threadIdx.x;
  const int lane = tid & 63;
  const int wid = tid >> 6;
  const int wm = (wid >> 1) * 64, wn = (wid & 1) * 64;
  const int l32 = lane & 31;
  const int khi = lane >> 5;

  const unsigned short* ga[4];
  #pragma unroll
  for (int i = 0; i < 4; ++i) {
    int r = wid * 32 + i * 8 + (lane >> 3);
    ga[i] = xb + (size_t)ids[m0 + r] * DD + (((lane & 7) ^ SW(r)) << 3);
  }

  const int b_f4 = (tid & 31) * 4;
  const int b_k8 = (tid >> 5) * 8;
  const float* wb1 = w1 + (size_t)expert * DD * FF + n0 + b_f4 + (size_t)b_k8 * FF;
  const float* wb3 = w3 + (size_t)expert * DD * FF + n0 + b_f4 + (size_t)b_k8 * FF;

  v4f r1[8], r3[8];
  #define G1_ALDS(KT) { _Pragma("unroll") for (int i_ = 0; i_ < 4; ++i_)        \
      gload_lds16(ga[i_] + (size_t)(KT) * BK,                                   \
                  (char*)sA + (wid * 32 + i_ * 8) * 128); }
  #define G1_BL(KT) {                                                           \
      const float* p_ = wb1 + (size_t)(KT) * BK * FF;                           \
      _Pragma("unroll") for (int j_ = 0; j_ < 8; ++j_)                          \
        r1[j_] = *(const v4f*)(p_ + (size_t)j_ * FF);                           \
      p_ = wb3 + (size_t)(KT) * BK * FF;                                        \
      _Pragma("unroll") for (int j_ = 0; j_ < 8; ++j_)                          \
        r3[j_] = *(const v4f*)(p_ + (size_t)j_ * FF); }
  #define G1_BW() { _Pragma("unroll") for (int c_ = 0; c_ < 4; ++c_) {          \
      v8s h1_, h3_;                                                             \
      _Pragma("unroll") for (int j_ = 0; j_ < 8; ++j_) {                        \
        h1_[j_] = f2bf(r1[j_][c_]); h3_[j_] = f2bf(r3[j_][c_]); }               \
      *(v8s*)((char*)sB0 + SWZ(b_f4 + c_, b_k8 * 2)) = h1_;                     \
      *(v8s*)((char*)sB1 + SWZ(b_f4 + c_, b_k8 * 2)) = h3_; } }

  v16f acc1[2][2], acc3[2][2];
  #pragma unroll
  for (int i = 0; i < 2; ++i)
    #pragma unroll
    for (int j = 0; j < 2; ++j) {
      acc1[i][j] = (v16f)(0.f);
      acc3[i][j] = (v16f)(0.f);
    }

  G1_BL(0);                        // B(0) prefetch

  for (int kt = 0; kt < DD / BK; ++kt) {
    G1_ALDS(kt);                   // A(kt) -> sA async, zero VGPR
    SCHEDB();
    G1_BW();                       // consume B(kt) regs (cvt+write)
    if (kt + 1 < DD / BK) {
      G1_BL(kt + 1);               // issue B(kt+1); flies across compute
      SCHEDB();
      VMCNT16();                   // wait the 4 A-gloads only
    } else {
      VMCNT0();
    }
    LGKM0(); BARR();
    SCHEDB();
    #pragma unroll
    for (int ks = 0; ks < 4; ++ks) {
      const int kb = (ks * 2 + khi) * 16;
      v8s a[2], b1[2], b3[2];
      #pragma unroll
      for (int m = 0; m < 2; ++m)
        a[m] = *(const v8s*)((const char*)sA + SWZ(wm + m * 32 + l32, kb));
      #pragma unroll
      for (int n = 0; n < 2; ++n) {
        b1[n] = *(const v8s*)((const char*)sB0 + SWZ(wn + n * 32 + l32, kb));
        b3[n] = *(const v8s*)((const char*)sB1 + SWZ(wn + n * 32 + l32, kb));
      }
      #pragma unroll
      for (int m = 0; m < 2; ++m)
        #pragma unroll
        for (int n = 0; n < 2; ++n) {
          acc1[m][n] = __builtin_amdgcn_mfma_f32_32x32x16_bf16(a[m], b1[n], acc1[m][n], 0, 0, 0);
          acc3[m][n] = __builtin_amdgcn_mfma_f32_32x32x16_bf16(a[m], b3[n], acc3[m][n], 0, 0, 0);
        }
    }
    BARR();                        // all waves done reading sA/sB
  }
  // C/D layout (32x32): col = lane&31, row = (r&3) + 8*(r>>2) + 4*(lane>>5)
  #pragma unroll
  for (int m = 0; m < 2; ++m)
    #pragma unroll
    for (int n = 0; n < 2; ++n)
      #pragma unroll
      for (int r = 0; r < 16; ++r) {
        int row = wm + m * 32 + (r & 3) + 8 * (r >> 2) + 4 * khi;
        int col = wn + n * 32 + l32;
        float g = acc1[m][n][r];
        float u = acc3[m][n][r];
        float hv = (g / (1.f + expf(-g))) * u;
        H[(size_t)(m0 + row) * FF + (n0 + col)] = (unsigned short)f2bf(hv);
      }
}

// ---------------- GEMM2: O[row] = H[row] @ W2 (raw, unweighted) ----------------
// R15/R17 verbatim: single B panel, plain bf16 stores to O (atomic-free).
__global__ __launch_bounds__(256, 2) void gemm2_k(
    const unsigned short* __restrict__ H, const float* __restrict__ w2,
    const int* __restrict__ counts, const int* __restrict__ rowoff,
    unsigned short* __restrict__ O) {
  int nt, mt;
  xcd_map(&nt, &mt);
  const int expert = find_expert(counts, rowoff, mt);
  if (expert < 0) return;
  const int m0 = mt * BM, n0 = nt * BN;

  __shared__ unsigned short sA[BM * BK];
  __shared__ unsigned short sB[BN * BK];

  const int tid = threadIdx.x;
  const int lane = tid & 63;
  const int wid = tid >> 6;
  const int wm = (wid >> 1) * 64, wn = (wid & 1) * 64;
  const int l32 = lane & 31;
  const int khi = lane >> 5;

  const unsigned short* ga[4];
  #pragma unroll
  for (int i = 0; i < 4; ++i) {
    int r = wid * 32 + i * 8 + (lane >> 3);
    ga[i] = H + (size_t)(m0 + r) * FF + (((lane & 7) ^ SW(r)) << 3);
  }

  const int b_f4 = (tid & 31) * 4;   // output cols (d)
  const int b_k8 = (tid >> 5) * 8;   // k rows (f)
  const float* wb = w2 + (size_t)expert * FF * DD + n0 + b_f4 + (size_t)b_k8 * DD;

  v4f rb[8];
  #define G2_ALDS(KT) { _Pragma("unroll") for (int i_ = 0; i_ < 4; ++i_)        \
      gload_lds16(ga[i_] + (size_t)(KT) * BK,                                   \
                  (char*)sA + (wid * 32 + i_ * 8) * 128); }
  #define G2_BL(KT) { const float* p_ = wb + (size_t)(KT) * BK * DD;            \
      _Pragma("unroll") for (int j_ = 0; j_ < 8; ++j_)                          \
        rb[j_] = *(const v4f*)(p_ + (size_t)j_ * DD); }
  #define G2_BW() { _Pragma("unroll") for (int c_ = 0; c_ < 4; ++c_) {          \
      v8s h_;                                                                   \
      _Pragma("unroll") for (int j_ = 0; j_ < 8; ++j_) h_[j_] = f2bf(rb[j_][c_]);\
      *(v8s*)((char*)sB + SWZ(b_f4 + c_, b_k8 * 2)) = h_; } }

  v16f acc[2][2];
  #pragma unroll
  for (int i = 0; i < 2; ++i)
    #pragma unroll
    for (int j = 0; j < 2; ++j) acc[i][j] = (v16f)(0.f);

  G2_BL(0);

  for (int kt = 0; kt < FF / BK; ++kt) {
    G2_ALDS(kt);
    SCHEDB();
    G2_BW();
    if (kt + 1 < FF / BK) {
      G2_BL(kt + 1);
      SCHEDB();
      VMCNT8();                    // wait the 4 A-gloads only
    } else {
      VMCNT0();
    }
    LGKM0(); BARR();
    SCHEDB();
    #pragma unroll
    for (int ks = 0; ks < 4; ++ks) {
      const int kb = (ks * 2 + khi) * 16;
      v8s a[2], b[2];
      #pragma unroll
      for (int m = 0; m < 2; ++m)
        a[m] = *(const v8s*)((const char*)sA + SWZ(wm + m * 32 + l32, kb));
      #pragma unroll
      for (int n = 0; n < 2; ++n)
        b[n] = *(const v8s*)((const char*)sB + SWZ(wn + n * 32 + l32, kb));
      #pragma unroll
      for (int m = 0; m < 2; ++m)
        #pragma unroll
        for (int n = 0; n < 2; ++n)
          acc[m][n] = __builtin_amdgcn_mfma_f32_32x32x16_bf16(a[m], b[n], acc[m][n], 0, 0, 0);
    }
    BARR();
  }

  // epilogue: raw bf16 stores (coalesced)
  #pragma unroll
  for (int m = 0; m < 2; ++m)
    #pragma unroll
    for (int r = 0; r < 16; ++r) {
      int row = m0 + wm + m * 32 + (r & 3) + 8 * (r >> 2) + 4 * khi;
      #pragma unroll
      for (int n = 0; n < 2; ++n)
        O[(size_t)row * DD + n0 + wn + n * 32 + l32] =
            (unsigned short)f2bf(acc[m][n][r]);
    }
}

// ---------------- combine: out[t] = w0*O[s0] + w1*O[s1] ----------------
__global__ __launch_bounds__(256) void combine_k(
    const unsigned short* __restrict__ O, const int* __restrict__ slot,
    const float* __restrict__ wts, float* __restrict__ out) {
  const int t = blockIdx.x;
  const int d = threadIdx.x * 8;
  const int s0 = slot[2 * t], s1 = slot[2 * t + 1];
  const float w0 = wts[s0], w1 = wts[s1];
  v8s a = *(const v8s*)(O + (size_t)s0 * DD + d);
  v8s b = *(const v8s*)(O + (size_t)s1 * DD + d);
  v4f o0, o1;
  #pragma unroll
  for (int j = 0; j < 4; ++j) {
    o0[j] = w0 * bf2f((unsigned short)a[j]) + w1 * bf2f((unsigned short)b[j]);
    o1[j] = w0 * bf2f((unsigned short)a[j + 4]) + w1 * bf2f((unsigned short)b[j + 4]);
  }
  float* op = out + (size_t)t * DD + d;
  *(v4f*)op = o0;
  *(v4f*)(op + 4) = o1;
}

extern "C" void kernel_launch(void* const* d_in, const int* in_sizes, int n_in,
                              void* d_out, int out_size, void* d_ws, size_t ws_size,
                              hipStream_t stream) {
  const float* x  = (const float*)d_in[0];
  const float* gw = (const float*)d_in[1];
  const float* w1 = (const float*)d_in[2];
  const float* w3 = (const float*)d_in[3];
  const float* w2 = (const float*)d_in[4];
  float* out = (float*)d_out;
  char* ws = (char*)d_ws;

  int*   counts = (int*)(ws + WS_COUNTS);
  int*   fill   = (int*)(ws + WS_FILL);
  int*   rowoff = (int*)(ws + WS_ROWOFF);
  int*   tope   = (int*)(ws + WS_TOPE);
  float* topw   = (float*)(ws + WS_TOPW);
  int*   ids    = (int*)(ws + WS_IDS);
  float* wts    = (float*)(ws + WS_WTS);
  int*   slot   = (int*)(ws + WS_SLOT);
  unsigned short* xb = (unsigned short*)(ws + WS_XB);
  unsigned short* H  = (unsigned short*)(ws + WS_H);
  unsigned short* O  = (unsigned short*)(ws + WS_O);

  hipMemsetAsync(ws, 0, WS_ZERO, stream);

  router_k<<<T_TOK / 4, 256, 0, stream>>>(x, gw, counts, tope, topw, xb);
  offsets_k<<<1, 64, 0, stream>>>(counts, rowoff);
  scatter_k<<<T_TOK / 256, 256, 0, stream>>>(tope, topw, rowoff, fill, ids, wts, slot);
  gemm1_k<<<dim3(FF / BN, MT_MAX), 256, 0, stream>>>(xb, w1, w3, counts, rowoff, ids, H);
  gemm2_k<<<dim3(DD / BN, MT_MAX), 256, 0, stream>>>(H, w2, counts, rowoff, O);
  combine_k<<<T_TOK, 256, 0, stream>>>(O, slot, wts, out);
}